// Round 1
// baseline (1106.567 us; speedup 1.0000x reference)
//
#include <hip/hip_runtime.h>

#define BS 8192
#define C 23
#define F 1024
#define CF (C*F)        // 23552
#define CF4 (CF/4)      // 5888
#define F4 (F/4)        // 256
#define NB 32           // batch chunks for pass-1 partials
#define BPB (BS/NB)     // 256
#define EPSV 1e-5f

// ---------------- pass 1: per-(c,f) partial sum / sumsq over a batch chunk ----------------
// grid: NB*C blocks (blk = bc*C + c), 256 threads, thread t owns float4 f-index t
__global__ __launch_bounds__(256) void k1_partial(const float* __restrict__ x,
                                                  float* __restrict__ psum,
                                                  float* __restrict__ pss) {
    const int blk = blockIdx.x;
    const int bc  = blk / C;
    const int c   = blk % C;
    const int t   = threadIdx.x;
    const float4* x4 = (const float4*)x;
    const float4* xp = x4 + (size_t)(bc * BPB) * CF4 + (size_t)c * F4 + t;
    float sx = 0.f, sy = 0.f, sz = 0.f, sw = 0.f;
    float qx = 0.f, qy = 0.f, qz = 0.f, qw = 0.f;
#pragma unroll 8
    for (int i = 0; i < BPB; ++i) {
        float4 v = xp[(size_t)i * CF4];
        sx += v.x; sy += v.y; sz += v.z; sw += v.w;
        qx += v.x * v.x; qy += v.y * v.y; qz += v.z * v.z; qw += v.w * v.w;
    }
    float4* ps4 = (float4*)psum;
    float4* pq4 = (float4*)pss;
    ps4[(size_t)blk * F4 + t] = make_float4(sx, sy, sz, sw);
    pq4[(size_t)blk * F4 + t] = make_float4(qx, qy, qz, qw);
}

// ---------------- pass 1b: reduce partials -> w[c,f] = rstd1*gamma1*W1, d[c] = dot(mean1, w) ----------------
// grid: C blocks, 256 threads, thread t owns float4 f-index t
__global__ __launch_bounds__(256) void k2_stats(const float* __restrict__ psum,
                                                const float* __restrict__ pss,
                                                const float* __restrict__ gamma1,
                                                const float* __restrict__ W1,
                                                float* __restrict__ w,
                                                float* __restrict__ d) {
    const int c = blockIdx.x;
    const int t = threadIdx.x;
    const float4* ps4 = (const float4*)psum;
    const float4* pq4 = (const float4*)pss;
    float sx = 0.f, sy = 0.f, sz = 0.f, sw = 0.f;
    float qx = 0.f, qy = 0.f, qz = 0.f, qw = 0.f;
    for (int bc = 0; bc < NB; ++bc) {
        float4 a = ps4[(size_t)(bc * C + c) * F4 + t];
        float4 b = pq4[(size_t)(bc * C + c) * F4 + t];
        sx += a.x; sy += a.y; sz += a.z; sw += a.w;
        qx += b.x; qy += b.y; qz += b.z; qw += b.w;
    }
    const float inv = 1.0f / (float)BS;
    float mx = sx * inv, my = sy * inv, mz = sz * inv, mw = sw * inv;
    float vx = fmaxf(qx * inv - mx * mx, 0.f);
    float vy = fmaxf(qy * inv - my * my, 0.f);
    float vz = fmaxf(qz * inv - mz * mz, 0.f);
    float vw = fmaxf(qw * inv - mw * mw, 0.f);
    const float4 g  = ((const float4*)gamma1)[(size_t)c * F4 + t];
    const float4 w1 = ((const float4*)W1)[(size_t)c * F4 + t];
    float4 wv;
    wv.x = rsqrtf(vx + EPSV) * g.x * w1.x;
    wv.y = rsqrtf(vy + EPSV) * g.y * w1.y;
    wv.z = rsqrtf(vz + EPSV) * g.z * w1.z;
    wv.w = rsqrtf(vw + EPSV) * g.w * w1.w;
    ((float4*)w)[(size_t)c * F4 + t] = wv;
    float dot = mx * wv.x + my * wv.y + mz * wv.z + mw * wv.w;
    __shared__ float red[256];
    red[t] = dot;
    __syncthreads();
    for (int off = 128; off > 0; off >>= 1) {
        if (t < off) red[t] += red[t + off];
        __syncthreads();
    }
    if (t == 0) d[c] = red[0];
}

// ---------------- pass 2: hc[c][b] = sum_f x[b,c,f]*w[c,f] - d[c] ----------------
// one wave per (b,c) row; grid: BS*C/4 blocks of 256 (4 waves)
__global__ __launch_bounds__(256) void k3_dot(const float* __restrict__ x,
                                              const float* __restrict__ w,
                                              const float* __restrict__ d,
                                              float* __restrict__ hc) {
    const int wave = threadIdx.x >> 6;
    const int lane = threadIdx.x & 63;
    const int r = blockIdx.x * 4 + wave;   // 0 .. BS*C-1
    const int b = r / C;
    const int c = r % C;
    const float4* xr = (const float4*)x + (size_t)b * CF4 + (size_t)c * F4;
    const float4* wr = (const float4*)w + (size_t)c * F4;
    float acc = 0.f;
#pragma unroll
    for (int k = 0; k < 4; ++k) {
        float4 xv = xr[lane + 64 * k];
        float4 wv = wr[lane + 64 * k];
        acc += xv.x * wv.x + xv.y * wv.y + xv.z * wv.z + xv.w * wv.w;
    }
#pragma unroll
    for (int off = 32; off > 0; off >>= 1) acc += __shfl_down(acc, off, 64);
    if (lane == 0) hc[(size_t)c * BS + b] = acc - d[c];
}

// ---------------- pass 3: per-channel batch stats of hc -> mean2[c], s[c] ----------------
__global__ __launch_bounds__(256) void k4_stats2(const float* __restrict__ hc,
                                                 const float* __restrict__ gamma2,
                                                 const float* __restrict__ W2,
                                                 float* __restrict__ mean2,
                                                 float* __restrict__ sc) {
    const int c = blockIdx.x;
    const int t = threadIdx.x;
    float s = 0.f, q = 0.f;
    for (int i = t; i < BS; i += 256) {
        float v = hc[(size_t)c * BS + i];
        s += v;
        q += v * v;
    }
    __shared__ float rs[256], rq[256];
    rs[t] = s; rq[t] = q;
    __syncthreads();
    for (int off = 128; off > 0; off >>= 1) {
        if (t < off) { rs[t] += rs[t + off]; rq[t] += rq[t + off]; }
        __syncthreads();
    }
    if (t == 0) {
        float m = rs[0] / (float)BS;
        float v = fmaxf(rq[0] / (float)BS - m * m, 0.f);
        mean2[c] = m;
        sc[c] = gamma2[c] * rsqrtf(v + EPSV) * W2[c];
    }
}

// ---------------- pass 4: out[b] = sum_c s[c]*(hc[c][b]-mean2[c]) + K ----------------
__global__ __launch_bounds__(256) void k5_out(const float* __restrict__ hc,
                                              const float* __restrict__ mean2,
                                              const float* __restrict__ sc,
                                              const float* __restrict__ beta2,
                                              const float* __restrict__ W2,
                                              const float* __restrict__ b2,
                                              float* __restrict__ out) {
    const int b = blockIdx.x * 256 + threadIdx.x;
    float acc = 0.f;
#pragma unroll
    for (int c = 0; c < C; ++c) acc += sc[c] * (hc[(size_t)c * BS + b] - mean2[c]);
    float K = b2[0];
#pragma unroll
    for (int c = 0; c < C; ++c) K += beta2[c] * W2[c];
    out[b] = acc + K;
}

extern "C" void kernel_launch(void* const* d_in, const int* in_sizes, int n_in,
                              void* d_out, int out_size, void* d_ws, size_t ws_size,
                              hipStream_t stream) {
    const float* x      = (const float*)d_in[0];
    const float* gamma1 = (const float*)d_in[1];
    // d_in[2] = beta1 : cancels in BN2 mean subtraction, unused
    const float* W1     = (const float*)d_in[3];
    // d_in[4] = b1    : cancels likewise, unused
    const float* gamma2 = (const float*)d_in[5];
    const float* beta2  = (const float*)d_in[6];
    const float* W2     = (const float*)d_in[7];
    const float* b2     = (const float*)d_in[8];
    float* out = (float*)d_out;

    float* ws = (float*)d_ws;
    // ws layout (float offsets), total ~6.9 MB
    float* psum  = ws + 0;          // NB*CF = 753664
    float* pss   = ws + 753664;     // NB*CF
    float* w     = ws + 1507328;    // CF = 23552
    float* d     = ws + 1530880;    // C (padded)
    float* hc    = ws + 1531904;    // BS*C = 188416
    float* mean2 = ws + 1720320;    // C (padded)
    float* sc    = ws + 1721344;    // C

    hipLaunchKernelGGL(k1_partial, dim3(NB * C), dim3(256), 0, stream, x, psum, pss);
    hipLaunchKernelGGL(k2_stats,   dim3(C),      dim3(256), 0, stream, psum, pss, gamma1, W1, w, d);
    hipLaunchKernelGGL(k3_dot,     dim3(BS * C / 4), dim3(256), 0, stream, x, w, d, hc);
    hipLaunchKernelGGL(k4_stats2,  dim3(C),      dim3(256), 0, stream, hc, gamma2, W2, mean2, sc);
    hipLaunchKernelGGL(k5_out,     dim3(BS / 256), dim3(256), 0, stream, hc, mean2, sc, beta2, W2, b2, out);
}